// Round 9
// baseline (413.974 us; speedup 1.0000x reference)
//
#include <hip/hip_runtime.h>
#include <hip/hip_bf16.h>

#define IN_FEAT 256
#define OUT_FEAT 32

// ---- single-level partition geometry ----
#define RBC 128          // rows per bucket
#define NC_MAX 1024      // max buckets (n_nodes <= 131072)
#define CAPC 2560        // capacity per bucket: lambda=2046 (+11 sigma)
#define L1_CHUNK 4096    // edges per part1 block (8 per thread, 512 threads)
#define SCH 2048         // consumer LDS staging chunk (entries)
#define OCAP 65536       // overflow list capacity
#define CNT_STRIDE 16    // u32 stride between counters (64B apart)

typedef __attribute__((ext_vector_type(8))) short short8;
typedef __attribute__((ext_vector_type(4))) float f32x4;

__device__ __forceinline__ unsigned cvt_pk_bf16(float lo, float hi) {
    unsigned r;
    asm volatile("v_cvt_pk_bf16_f32 %0, %1, %2" : "=v"(r) : "v"(lo), "v"(hi));
    return r;
}

// 8 independent global loads in ONE asm block: the 8 early-clobber outputs
// must coexist in registers -> the allocator cannot serialize the batch
// (rounds 5/7/8 failure: VGPR=12..24 proved MLP=1). voffset is a 32-bit
// byte offset against the uniform SGPR base (ISA 7: global_load_dword
// vdst, voffset, saddr).
__device__ __forceinline__ void gather8(const float* __restrict__ xbase,
    unsigned o0, unsigned o1, unsigned o2, unsigned o3,
    unsigned o4, unsigned o5, unsigned o6, unsigned o7,
    float& r0, float& r1, float& r2, float& r3,
    float& r4, float& r5, float& r6, float& r7)
{
    asm volatile(
        "global_load_dword %0, %8, %16\n\t"
        "global_load_dword %1, %9, %16\n\t"
        "global_load_dword %2, %10, %16\n\t"
        "global_load_dword %3, %11, %16\n\t"
        "global_load_dword %4, %12, %16\n\t"
        "global_load_dword %5, %13, %16\n\t"
        "global_load_dword %6, %14, %16\n\t"
        "global_load_dword %7, %15, %16\n\t"
        "s_waitcnt vmcnt(0)"
        : "=&v"(r0), "=&v"(r1), "=&v"(r2), "=&v"(r3),
          "=&v"(r4), "=&v"(r5), "=&v"(r6), "=&v"(r7)
        : "v"(o0), "v"(o1), "v"(o2), "v"(o3),
          "v"(o4), "v"(o5), "v"(o6), "v"(o7),
          "s"(xbase)
        : "memory");
}

// ---------------------------------------------------------------------------
// Kernel 1: x = feat @ W via bf16 MFMA (measured 27 us, unchanged).
// ---------------------------------------------------------------------------
__global__ __launch_bounds__(256) void gemm_mfma_kernel(
    const float* __restrict__ feat,
    const float* __restrict__ W,
    float* __restrict__ x,
    int n)
{
    __shared__ short sWT[OUT_FEAT][IN_FEAT + 8];

    const int tid = threadIdx.x;
    for (int i = tid; i < IN_FEAT * OUT_FEAT; i += 256) {
        const int k = i >> 5, c = i & 31;
        __hip_bfloat16 h = __float2bfloat16(W[i]);
        sWT[c][k] = *reinterpret_cast<short*>(&h);
    }
    __syncthreads();

    const int wid  = tid >> 6;
    const int lane = tid & 63;
    const int tile = blockIdx.x * 4 + wid;
    const int row0 = tile * 16;
    if (row0 >= n) return;

    const int l16 = lane & 15;
    const int lh  = lane >> 4;

    if (row0 + 16 <= n) {
        const int row = row0 + l16;
        const float4* fr = reinterpret_cast<const float4*>(feat) + (size_t)row * (IN_FEAT / 4);

        float4 ra[8][2];
        #pragma unroll
        for (int ks = 0; ks < 8; ++ks) {
            ra[ks][0] = fr[ks * 8 + lh * 2];
            ra[ks][1] = fr[ks * 8 + lh * 2 + 1];
        }

        f32x4 acc0 = {0.f, 0.f, 0.f, 0.f};
        f32x4 acc1 = {0.f, 0.f, 0.f, 0.f};

        #pragma unroll
        for (int ks = 0; ks < 8; ++ks) {
            union { short8 s; unsigned u[4]; } af;
            af.u[0] = cvt_pk_bf16(ra[ks][0].x, ra[ks][0].y);
            af.u[1] = cvt_pk_bf16(ra[ks][0].z, ra[ks][0].w);
            af.u[2] = cvt_pk_bf16(ra[ks][1].x, ra[ks][1].y);
            af.u[3] = cvt_pk_bf16(ra[ks][1].z, ra[ks][1].w);

            const int k0 = ks * 32 + lh * 8;
            short8 b0 = *reinterpret_cast<const short8*>(&sWT[l16][k0]);
            short8 b1 = *reinterpret_cast<const short8*>(&sWT[16 + l16][k0]);

            acc0 = __builtin_amdgcn_mfma_f32_16x16x32_bf16(af.s, b0, acc0, 0, 0, 0);
            acc1 = __builtin_amdgcn_mfma_f32_16x16x32_bf16(af.s, b1, acc1, 0, 0, 0);
        }

        #pragma unroll
        for (int r = 0; r < 4; ++r) {
            const size_t orow = (size_t)(row0 + lh * 4 + r) * OUT_FEAT;
            x[orow + l16]      = acc0[r];
            x[orow + 16 + l16] = acc1[r];
        }
    } else {
        const int rows = n - row0;
        for (int idx = lane; idx < rows * OUT_FEAT; idx += 64) {
            const int r = idx >> 5, j = idx & 31;
            float a = 0.f;
            for (int k = 0; k < IN_FEAT; ++k) {
                unsigned wb = ((unsigned)(unsigned short)sWT[j][k]) << 16;
                a += feat[(size_t)(row0 + r) * IN_FEAT + k] * __uint_as_float(wb);
            }
            x[(size_t)(row0 + r) * OUT_FEAT + j] = a;
        }
    }
}

// ---------------------------------------------------------------------------
// Kernel 2: partition edges into 128-row buckets (row>>7). 512 threads x
//   4096-edge chunk. LDS counting sort -> bucket-sorted coalesced copy-out.
//   Entry {meta=(row&127)<<17|col, valbits}.
// ---------------------------------------------------------------------------
__global__ __launch_bounds__(512) void part1_kernel(
    const float* __restrict__ vals,
    const int* __restrict__ erow,
    const int* __restrict__ ecol,
    uint2* __restrict__ buf1,
    unsigned* __restrict__ cnt1,
    unsigned* __restrict__ ocnt,
    uint4* __restrict__ obuf,
    int n_edges, int nc)
{
    __shared__ uint2 sE[L1_CHUNK];                 // 32 KB
    __shared__ unsigned short sBkt[L1_CHUNK];      // 8 KB
    __shared__ unsigned sHist[NC_MAX], sBase[NC_MAX], sCur[NC_MAX], sGBase[NC_MAX];  // 16 KB

    const int tid = threadIdx.x;
    const int chunk0 = blockIdx.x * L1_CHUNK;
    const int nq = n_edges >> 2;

    for (int b = tid; b < nc; b += 512) { sHist[b] = 0; sCur[b] = 0; }
    __syncthreads();

    int4 r4[2]; int4 c4[2]; float4 v4[2];
    #pragma unroll
    for (int i = 0; i < 2; ++i) {
        const int qi = (chunk0 >> 2) + tid + i * 512;
        if (qi < nq) {
            r4[i] = reinterpret_cast<const int4*>(erow)[qi];
            c4[i] = reinterpret_cast<const int4*>(ecol)[qi];
            v4[i] = reinterpret_cast<const float4*>(vals)[qi];
        } else {
            r4[i] = make_int4(-1, -1, -1, -1);
            c4[i] = make_int4(0, 0, 0, 0);
            v4[i] = make_float4(0.f, 0.f, 0.f, 0.f);
        }
    }

    #pragma unroll
    for (int i = 0; i < 2; ++i) {
        const int* rr = &r4[i].x;
        #pragma unroll
        for (int t = 0; t < 4; ++t)
            if (rr[t] >= 0) atomicAdd(&sHist[rr[t] >> 7], 1u);
    }
    __syncthreads();

    if (tid == 0) {
        unsigned s = 0;
        for (int b = 0; b < nc; ++b) { sBase[b] = s; s += sHist[b]; }
    }
    __syncthreads();

    for (int b = tid; b < nc; b += 512)
        sGBase[b] = sHist[b] ? atomicAdd(&cnt1[(size_t)b * CNT_STRIDE], sHist[b]) : 0u;
    __syncthreads();

    #pragma unroll
    for (int i = 0; i < 2; ++i) {
        const int*   rr = &r4[i].x;
        const int*   cc = &c4[i].x;
        const float* vv = &v4[i].x;
        #pragma unroll
        for (int t = 0; t < 4; ++t) {
            const int r = rr[t];
            if (r >= 0) {
                const int cb = r >> 7;
                unsigned p = sBase[cb] + atomicAdd(&sCur[cb], 1u);
                sE[p] = make_uint2(((unsigned)(r & 127) << 17) | (unsigned)cc[t],
                                   __float_as_uint(vv[t]));
                sBkt[p] = (unsigned short)cb;
            }
        }
    }
    __syncthreads();

    int total = n_edges - chunk0;
    if (total > L1_CHUNK) total = L1_CHUNK;
    for (int p = tid; p < total; p += 512) {
        const int cb = sBkt[p];
        const unsigned g = sGBase[cb] + (p - sBase[cb]);
        const uint2 e = sE[p];
        if (g < CAPC) {
            buf1[(size_t)cb * CAPC + g] = e;
        } else {
            unsigned o = atomicAdd(ocnt, 1u);
            if (o < OCAP)
                obuf[o] = make_uint4(((unsigned)cb << 7) | (e.x >> 17),
                                     e.x & 0x1FFFFu, e.y, 0u);
        }
    }

    if (blockIdx.x == 0 && tid < (n_edges & 3)) {
        const int e = (nq << 2) + tid;
        unsigned o = atomicAdd(ocnt, 1u);
        if (o < OCAP)
            obuf[o] = make_uint4((unsigned)erow[e], (unsigned)ecol[e],
                                 __float_as_uint(vals[e]), 0u);
    }
}

// ---------------------------------------------------------------------------
// Kernel 3: consumer. One block per 128-row bucket, 512 threads = 16 groups.
//   Inner loop: 8 LDS entry-reads -> 8-deep inline-asm gather batch (one
//   vmcnt(0) per 8 edges) -> 8 conflict-free LDS atomics. launch_bounds
//   (512,8) -> 4 blocks/CU (128KB LDS), VGPR capped at 64.
//   Success signal: VGPR >= 40.
// ---------------------------------------------------------------------------
__global__ __launch_bounds__(512, 8) void spmm_consumer_kernel(
    const uint2* __restrict__ buf1,
    const unsigned* __restrict__ cnt1,
    const float* __restrict__ x,
    float* __restrict__ out,
    int n_nodes)
{
    __shared__ float acc[RBC * OUT_FEAT];   // 16 KB
    __shared__ uint2 se[SCH];               // 16 KB

    const int tid = threadIdx.x;
    const int b = blockIdx.x;

    unsigned n = cnt1[(size_t)b * CNT_STRIDE];
    if (n > CAPC) n = CAPC;

    #pragma unroll
    for (int i = 0; i < (RBC * OUT_FEAT) / 512; ++i) acc[tid + i * 512] = 0.f;

    const uint2* eb = buf1 + (size_t)b * CAPC;
    const int g = tid >> 5;            // group 0..15
    const int j = tid & 31;            // feature
    const unsigned jb = (unsigned)(j << 2);   // byte offset of feature

    for (unsigned c0 = 0; c0 < n; c0 += SCH) {
        int m = (int)(n - c0);
        if (m > SCH) m = SCH;

        __syncthreads();   // previous chunk fully consumed
        for (int i = tid; i < m; i += 512) se[i] = eb[c0 + i];
        __syncthreads();

        int base = 0;
        for (; base + 128 <= m; base += 128) {
            const uint2 p0 = se[base + g];
            const uint2 p1 = se[base + g + 16];
            const uint2 p2 = se[base + g + 32];
            const uint2 p3 = se[base + g + 48];
            const uint2 p4 = se[base + g + 64];
            const uint2 p5 = se[base + g + 80];
            const uint2 p6 = se[base + g + 96];
            const uint2 p7 = se[base + g + 112];

            // byte offset = col*128 + j*4
            const unsigned q0 = ((p0.x & 0x1FFFFu) << 7) | jb;
            const unsigned q1 = ((p1.x & 0x1FFFFu) << 7) | jb;
            const unsigned q2 = ((p2.x & 0x1FFFFu) << 7) | jb;
            const unsigned q3 = ((p3.x & 0x1FFFFu) << 7) | jb;
            const unsigned q4 = ((p4.x & 0x1FFFFu) << 7) | jb;
            const unsigned q5 = ((p5.x & 0x1FFFFu) << 7) | jb;
            const unsigned q6 = ((p6.x & 0x1FFFFu) << 7) | jb;
            const unsigned q7 = ((p7.x & 0x1FFFFu) << 7) | jb;

            float x0, x1, x2, x3, x4, x5, x6, x7;
            gather8(x, q0, q1, q2, q3, q4, q5, q6, q7,
                    x0, x1, x2, x3, x4, x5, x6, x7);

            atomicAdd(&acc[((p0.x >> 17) & 127u) * OUT_FEAT + j], __uint_as_float(p0.y) * x0);
            atomicAdd(&acc[((p1.x >> 17) & 127u) * OUT_FEAT + j], __uint_as_float(p1.y) * x1);
            atomicAdd(&acc[((p2.x >> 17) & 127u) * OUT_FEAT + j], __uint_as_float(p2.y) * x2);
            atomicAdd(&acc[((p3.x >> 17) & 127u) * OUT_FEAT + j], __uint_as_float(p3.y) * x3);
            atomicAdd(&acc[((p4.x >> 17) & 127u) * OUT_FEAT + j], __uint_as_float(p4.y) * x4);
            atomicAdd(&acc[((p5.x >> 17) & 127u) * OUT_FEAT + j], __uint_as_float(p5.y) * x5);
            atomicAdd(&acc[((p6.x >> 17) & 127u) * OUT_FEAT + j], __uint_as_float(p6.y) * x6);
            atomicAdd(&acc[((p7.x >> 17) & 127u) * OUT_FEAT + j], __uint_as_float(p7.y) * x7);
        }
        // tail (< 128 entries)
        for (int i = base + g; i < m; i += 16) {
            const uint2 p = se[i];
            const float xv = x[(size_t)(p.x & 0x1FFFFu) * OUT_FEAT + j];
            atomicAdd(&acc[((p.x >> 17) & 127u) * OUT_FEAT + j],
                      __uint_as_float(p.y) * xv);
        }
    }
    __syncthreads();

    // full-coverage coalesced write of this bucket's 128 rows
    int valid = (n_nodes - b * RBC) * OUT_FEAT;
    if (valid > RBC * OUT_FEAT) valid = RBC * OUT_FEAT;
    const int v4n = valid >> 2;
    float4* out4 = reinterpret_cast<float4*>(out + (size_t)b * RBC * OUT_FEAT);
    const float4* a4 = reinterpret_cast<const float4*>(acc);
    if (tid < v4n)       out4[tid]       = a4[tid];
    if (tid + 512 < v4n) out4[tid + 512] = a4[tid + 512];
}

// ---------------------------------------------------------------------------
// Kernel 4: overflow cleanup (expected zero work).
// ---------------------------------------------------------------------------
__global__ __launch_bounds__(256) void oflow_kernel(
    const uint4* __restrict__ obuf,
    const unsigned* __restrict__ ocnt,
    const float* __restrict__ x,
    float* __restrict__ out)
{
    unsigned n = *ocnt;
    if (n > OCAP) n = OCAP;
    const long long total = (long long)n * OUT_FEAT;
    const long long stride = (long long)gridDim.x * blockDim.x;
    for (long long idx = blockIdx.x * (long long)blockDim.x + threadIdx.x;
         idx < total; idx += stride) {
        const int e = (int)(idx >> 5), j = (int)(idx & 31);
        uint4 p = obuf[e];
        atomicAdd(&out[(size_t)p.x * OUT_FEAT + j],
                  __uint_as_float(p.z) * x[(size_t)p.y * OUT_FEAT + j]);
    }
}

// ---------------------------------------------------------------------------
// Fallback: flat atomic scatter (measured 171 us) if ws/shape gate fails.
// ---------------------------------------------------------------------------
__global__ __launch_bounds__(256) void spmm_scatter_kernel(
    const float* __restrict__ vals,
    const int* __restrict__ erow,
    const int* __restrict__ ecol,
    const float* __restrict__ x,
    float* __restrict__ out,
    int n_edges)
{
    const long long idx = (long long)blockIdx.x * blockDim.x + threadIdx.x;
    const int e = (int)(idx >> 5);
    const int j = (int)(idx & 31);
    if (e >= n_edges) return;
    const float m = vals[e] * x[(size_t)ecol[e] * OUT_FEAT + j];
    atomicAdd(&out[(size_t)erow[e] * OUT_FEAT + j], m);
}

// ---------------------------------------------------------------------------
extern "C" void kernel_launch(void* const* d_in, const int* in_sizes, int n_in,
                              void* d_out, int out_size, void* d_ws, size_t ws_size,
                              hipStream_t stream)
{
    const float* feat = (const float*)d_in[0];
    const float* W    = (const float*)d_in[1];
    const float* vals = (const float*)d_in[2];
    const int*   erow = (const int*)d_in[3];
    const int*   ecol = (const int*)d_in[4];
    float* out = (float*)d_out;

    const int n_nodes = in_sizes[0] / IN_FEAT;
    const int n_edges = in_sizes[2];
    const int nc = (n_nodes + RBC - 1) / RBC;     // buckets (782)

    char* ws = (char*)d_ws;
    size_t off = 0;
    auto alloc = [&](size_t bytes) { size_t o = off; off = (off + bytes + 15) & ~(size_t)15; return o; };
    float*    x    = (float*)(ws + alloc((size_t)n_nodes * OUT_FEAT * sizeof(float)));
    uint2*    buf1 = (uint2*)(ws + alloc((size_t)nc * CAPC * sizeof(uint2)));
    size_t cnt_off = off;
    unsigned* cnt1 = (unsigned*)(ws + alloc((size_t)nc * CNT_STRIDE * sizeof(unsigned)));
    unsigned* ocnt = (unsigned*)(ws + alloc(sizeof(unsigned)));
    size_t cnt_end = (size_t)((char*)ocnt - ws) + 16;
    uint4*    obuf = (uint4*)(ws + alloc((size_t)OCAP * sizeof(uint4)));

    const double lam = (nc > 0) ? (double)n_edges / nc : 0.0;
    const bool sorted_path = (ws_size >= off) && (nc <= NC_MAX) &&
                             (lam + 8.0 * sqrt(lam + 1.0) <= (double)CAPC);

    // 1) x = feat @ W  (bf16 MFMA)
    {
        const int tiles = (n_nodes + 15) / 16;
        dim3 grid((tiles + 3) / 4);
        gemm_mfma_kernel<<<grid, 256, 0, stream>>>(feat, W, x, n_nodes);
    }

    if (sorted_path) {
        hipMemsetAsync(ws + cnt_off, 0, cnt_end - cnt_off, stream);

        const int nblk = (n_edges + L1_CHUNK - 1) / L1_CHUNK;
        part1_kernel<<<nblk, 512, 0, stream>>>(vals, erow, ecol, buf1, cnt1,
                                               ocnt, obuf, n_edges, nc);
        spmm_consumer_kernel<<<nc, 512, 0, stream>>>(buf1, cnt1, x, out, n_nodes);
        oflow_kernel<<<64, 256, 0, stream>>>(obuf, ocnt, x, out);
    } else {
        hipMemsetAsync(d_out, 0, (size_t)out_size * sizeof(float), stream);
        long long total = (long long)n_edges * OUT_FEAT;
        spmm_scatter_kernel<<<(unsigned)((total + 255) / 256), 256, 0, stream>>>(
            vals, erow, ecol, x, out, n_edges);
    }
}

// Round 10
// 294.808 us; speedup vs baseline: 1.4042x; 1.4042x over previous
//
#include <hip/hip_runtime.h>
#include <hip/hip_bf16.h>

#define IN_FEAT 256
#define OUT_FEAT 32

#define RBC 128          // rows per bucket
#define NC_MAX 1024      // max buckets (n_nodes <= 131072)
#define CAPC 2560        // capacity per bucket: lambda=2046 (+11 sigma)
#define L1_CHUNK 4096    // edges per part1 block
#define OCAP 65536       // overflow list capacity
#define CNT_STRIDE 16    // u32 stride between counters (64B apart)
#define SLOTS 16         // edges per scatter_seg block

typedef __attribute__((ext_vector_type(8))) short short8;
typedef __attribute__((ext_vector_type(4))) float f32x4;

__device__ __forceinline__ unsigned cvt_pk_bf16(float lo, float hi) {
    unsigned r;
    asm volatile("v_cvt_pk_bf16_f32 %0, %1, %2" : "=v"(r) : "v"(lo), "v"(hi));
    return r;
}

// ---------------------------------------------------------------------------
// Kernel 1: x = feat @ W via bf16 MFMA (measured 27 us, unchanged).
// ---------------------------------------------------------------------------
__global__ __launch_bounds__(256) void gemm_mfma_kernel(
    const float* __restrict__ feat,
    const float* __restrict__ W,
    float* __restrict__ x,
    int n)
{
    __shared__ short sWT[OUT_FEAT][IN_FEAT + 8];

    const int tid = threadIdx.x;
    for (int i = tid; i < IN_FEAT * OUT_FEAT; i += 256) {
        const int k = i >> 5, c = i & 31;
        __hip_bfloat16 h = __float2bfloat16(W[i]);
        sWT[c][k] = *reinterpret_cast<short*>(&h);
    }
    __syncthreads();

    const int wid  = tid >> 6;
    const int lane = tid & 63;
    const int tile = blockIdx.x * 4 + wid;
    const int row0 = tile * 16;
    if (row0 >= n) return;

    const int l16 = lane & 15;
    const int lh  = lane >> 4;

    if (row0 + 16 <= n) {
        const int row = row0 + l16;
        const float4* fr = reinterpret_cast<const float4*>(feat) + (size_t)row * (IN_FEAT / 4);

        float4 ra[8][2];
        #pragma unroll
        for (int ks = 0; ks < 8; ++ks) {
            ra[ks][0] = fr[ks * 8 + lh * 2];
            ra[ks][1] = fr[ks * 8 + lh * 2 + 1];
        }

        f32x4 acc0 = {0.f, 0.f, 0.f, 0.f};
        f32x4 acc1 = {0.f, 0.f, 0.f, 0.f};

        #pragma unroll
        for (int ks = 0; ks < 8; ++ks) {
            union { short8 s; unsigned u[4]; } af;
            af.u[0] = cvt_pk_bf16(ra[ks][0].x, ra[ks][0].y);
            af.u[1] = cvt_pk_bf16(ra[ks][0].z, ra[ks][0].w);
            af.u[2] = cvt_pk_bf16(ra[ks][1].x, ra[ks][1].y);
            af.u[3] = cvt_pk_bf16(ra[ks][1].z, ra[ks][1].w);

            const int k0 = ks * 32 + lh * 8;
            short8 b0 = *reinterpret_cast<const short8*>(&sWT[l16][k0]);
            short8 b1 = *reinterpret_cast<const short8*>(&sWT[16 + l16][k0]);

            acc0 = __builtin_amdgcn_mfma_f32_16x16x32_bf16(af.s, b0, acc0, 0, 0, 0);
            acc1 = __builtin_amdgcn_mfma_f32_16x16x32_bf16(af.s, b1, acc1, 0, 0, 0);
        }

        #pragma unroll
        for (int r = 0; r < 4; ++r) {
            const size_t orow = (size_t)(row0 + lh * 4 + r) * OUT_FEAT;
            x[orow + l16]      = acc0[r];
            x[orow + 16 + l16] = acc1[r];
        }
    } else {
        const int rows = n - row0;
        for (int idx = lane; idx < rows * OUT_FEAT; idx += 64) {
            const int r = idx >> 5, j = idx & 31;
            float a = 0.f;
            for (int k = 0; k < IN_FEAT; ++k) {
                unsigned wb = ((unsigned)(unsigned short)sWT[j][k]) << 16;
                a += feat[(size_t)(row0 + r) * IN_FEAT + k] * __uint_as_float(wb);
            }
            x[(size_t)(row0 + r) * OUT_FEAT + j] = a;
        }
    }
}

// ---------------------------------------------------------------------------
// Kernel 2: partition edges into 128-row buckets (row>>7). Proven ~28us.
//   Entry {meta=(row&127)<<17|col, valbits}.
// ---------------------------------------------------------------------------
__global__ __launch_bounds__(512) void part1_kernel(
    const float* __restrict__ vals,
    const int* __restrict__ erow,
    const int* __restrict__ ecol,
    uint2* __restrict__ buf1,
    unsigned* __restrict__ cnt1,
    unsigned* __restrict__ ocnt,
    uint4* __restrict__ obuf,
    int n_edges, int nc)
{
    __shared__ uint2 sE[L1_CHUNK];                 // 32 KB
    __shared__ unsigned short sBkt[L1_CHUNK];      // 8 KB
    __shared__ unsigned sHist[NC_MAX], sBase[NC_MAX], sCur[NC_MAX], sGBase[NC_MAX];

    const int tid = threadIdx.x;
    const int chunk0 = blockIdx.x * L1_CHUNK;
    const int nq = n_edges >> 2;

    for (int b = tid; b < nc; b += 512) { sHist[b] = 0; sCur[b] = 0; }
    __syncthreads();

    int4 r4[2]; int4 c4[2]; float4 v4[2];
    #pragma unroll
    for (int i = 0; i < 2; ++i) {
        const int qi = (chunk0 >> 2) + tid + i * 512;
        if (qi < nq) {
            r4[i] = reinterpret_cast<const int4*>(erow)[qi];
            c4[i] = reinterpret_cast<const int4*>(ecol)[qi];
            v4[i] = reinterpret_cast<const float4*>(vals)[qi];
        } else {
            r4[i] = make_int4(-1, -1, -1, -1);
            c4[i] = make_int4(0, 0, 0, 0);
            v4[i] = make_float4(0.f, 0.f, 0.f, 0.f);
        }
    }

    #pragma unroll
    for (int i = 0; i < 2; ++i) {
        const int* rr = &r4[i].x;
        #pragma unroll
        for (int t = 0; t < 4; ++t)
            if (rr[t] >= 0) atomicAdd(&sHist[rr[t] >> 7], 1u);
    }
    __syncthreads();

    if (tid == 0) {
        unsigned s = 0;
        for (int b = 0; b < nc; ++b) { sBase[b] = s; s += sHist[b]; }
    }
    __syncthreads();

    for (int b = tid; b < nc; b += 512)
        sGBase[b] = sHist[b] ? atomicAdd(&cnt1[(size_t)b * CNT_STRIDE], sHist[b]) : 0u;
    __syncthreads();

    #pragma unroll
    for (int i = 0; i < 2; ++i) {
        const int*   rr = &r4[i].x;
        const int*   cc = &c4[i].x;
        const float* vv = &v4[i].x;
        #pragma unroll
        for (int t = 0; t < 4; ++t) {
            const int r = rr[t];
            if (r >= 0) {
                const int cb = r >> 7;
                unsigned p = sBase[cb] + atomicAdd(&sCur[cb], 1u);
                sE[p] = make_uint2(((unsigned)(r & 127) << 17) | (unsigned)cc[t],
                                   __float_as_uint(vv[t]));
                sBkt[p] = (unsigned short)cb;
            }
        }
    }
    __syncthreads();

    int total = n_edges - chunk0;
    if (total > L1_CHUNK) total = L1_CHUNK;
    for (int p = tid; p < total; p += 512) {
        const int cb = sBkt[p];
        const unsigned g = sGBase[cb] + (p - sBase[cb]);
        const uint2 e = sE[p];
        if (g < CAPC) {
            buf1[(size_t)cb * CAPC + g] = e;
        } else {
            unsigned o = atomicAdd(ocnt, 1u);
            if (o < OCAP)
                obuf[o] = make_uint4(((unsigned)cb << 7) | (e.x >> 17),
                                     e.x & 0x1FFFFu, e.y, 0u);
        }
    }

    if (blockIdx.x == 0 && tid < (n_edges & 3)) {
        const int e = (nq << 2) + tid;
        unsigned o = atomicAdd(ocnt, 1u);
        if (o < OCAP)
            obuf[o] = make_uint4((unsigned)erow[e], (unsigned)ecol[e],
                                 __float_as_uint(vals[e]), 0u);
    }
}

// ---------------------------------------------------------------------------
// Kernel 3: in-place counting sort of each bucket by local row (7-bit key).
//   Reads all entries to registers first, then LDS scatter, then coalesced
//   write-back to the SAME buffer (block owns its bucket exclusively).
//   After this, the edge stream is globally sorted by row.
// ---------------------------------------------------------------------------
__global__ __launch_bounds__(512) void sort_kernel(
    uint2* __restrict__ buf1,
    const unsigned* __restrict__ cnt1)
{
    __shared__ uint2 sorted[CAPC];                       // 20 KB
    __shared__ unsigned h[RBC], base[RBC], cur[RBC];

    const int tid = threadIdx.x;
    const int b = blockIdx.x;
    unsigned n = cnt1[(size_t)b * CNT_STRIDE];
    if (n > CAPC) n = CAPC;
    uint2* eb = buf1 + (size_t)b * CAPC;

    if (tid < RBC) { h[tid] = 0; cur[tid] = 0; }
    __syncthreads();

    uint2 e[5];   // 5*512 = 2560 = CAPC
    #pragma unroll
    for (int i = 0; i < 5; ++i) {
        const int p = tid + i * 512;
        e[i] = (p < (int)n) ? eb[p] : make_uint2(0xFFFFFFFFu, 0u);  // valid meta < 2^24
    }
    #pragma unroll
    for (int i = 0; i < 5; ++i)
        if (e[i].x != 0xFFFFFFFFu) atomicAdd(&h[(e[i].x >> 17) & 127u], 1u);
    __syncthreads();

    if (tid == 0) {
        unsigned s = 0;
        for (int r = 0; r < RBC; ++r) { base[r] = s; s += h[r]; }
    }
    __syncthreads();

    #pragma unroll
    for (int i = 0; i < 5; ++i) {
        if (e[i].x != 0xFFFFFFFFu) {
            const unsigned r = (e[i].x >> 17) & 127u;
            const unsigned p = base[r] + atomicAdd(&cur[r], 1u);
            sorted[p] = e[i];
        }
    }
    __syncthreads();

    for (int i = tid; i < (int)n; i += 512) eb[i] = sorted[i];
}

// ---------------------------------------------------------------------------
// Kernel 4: segment-reduced scatter over the sorted stream.
//   Block = 16 consecutive sorted edges x 32 features (512 threads). Gather +
//   msg exactly like the proven flat scatter; then a 4-round LDS segmented
//   scan merges same-row contributions; one global atomic per row-run.
//   Expected atomics: ~1.94 runs/window -> 51.2M -> ~6.2M lane-ops (8x cut).
// ---------------------------------------------------------------------------
__global__ __launch_bounds__(512) void scatter_seg_kernel(
    const uint2* __restrict__ buf1,
    const unsigned* __restrict__ cnt1,
    const float* __restrict__ x,
    float* __restrict__ out)
{
    const int tid = threadIdx.x;
    const int s = tid >> 5;         // slot 0..15
    const int j = tid & 31;         // feature
    const int b = blockIdx.x / (CAPC / SLOTS);
    const int w = blockIdx.x % (CAPC / SLOTS);

    unsigned n = cnt1[(size_t)b * CNT_STRIDE];
    if (n > CAPC) n = CAPC;
    const int off0 = w * SLOTS;
    if (off0 >= (int)n) return;     // block-uniform early exit (before barriers)

    __shared__ int   srow[SLOTS];
    __shared__ float sval[SLOTS][32];

    const int gi = off0 + s;
    const bool valid = gi < (int)n;
    float m = 0.f;
    int row = -1;
    if (valid) {
        const uint2 e = buf1[(size_t)b * CAPC + gi];
        const unsigned col = e.x & 0x1FFFFu;
        row = b * RBC + (int)((e.x >> 17) & 127u);
        m = __uint_as_float(e.y) * x[(size_t)col * OUT_FEAT + j];
    }
    if (j == 0) srow[s] = row;
    sval[s][j] = m;
    __syncthreads();

    // Segmented inclusive scan over slots (rows are contiguous runs: equality
    // test == same segment). 4 rounds, read-then-sync-then-write.
    #pragma unroll
    for (int d = 1; d < SLOTS; d <<= 1) {
        float add = 0.f;
        if (s >= d && row != -1 && srow[s - d] == row) add = sval[s - d][j];
        __syncthreads();
        sval[s][j] += add;
        __syncthreads();
    }

    // Emit at the last slot of each run.
    if (valid && (s == SLOTS - 1 || srow[s + 1] != row))
        atomicAdd(&out[(size_t)row * OUT_FEAT + j], sval[s][j]);
}

// ---------------------------------------------------------------------------
// Kernel 5: overflow cleanup (expected zero work).
// ---------------------------------------------------------------------------
__global__ __launch_bounds__(256) void oflow_kernel(
    const uint4* __restrict__ obuf,
    const unsigned* __restrict__ ocnt,
    const float* __restrict__ x,
    float* __restrict__ out)
{
    unsigned n = *ocnt;
    if (n > OCAP) n = OCAP;
    const long long total = (long long)n * OUT_FEAT;
    const long long stride = (long long)gridDim.x * blockDim.x;
    for (long long idx = blockIdx.x * (long long)blockDim.x + threadIdx.x;
         idx < total; idx += stride) {
        const int e = (int)(idx >> 5), j = (int)(idx & 31);
        uint4 p = obuf[e];
        atomicAdd(&out[(size_t)p.x * OUT_FEAT + j],
                  __uint_as_float(p.z) * x[(size_t)p.y * OUT_FEAT + j]);
    }
}

// ---------------------------------------------------------------------------
// Fallback: flat atomic scatter (measured 171 us) if ws/shape gate fails.
// ---------------------------------------------------------------------------
__global__ __launch_bounds__(256) void spmm_scatter_kernel(
    const float* __restrict__ vals,
    const int* __restrict__ erow,
    const int* __restrict__ ecol,
    const float* __restrict__ x,
    float* __restrict__ out,
    int n_edges)
{
    const long long idx = (long long)blockIdx.x * blockDim.x + threadIdx.x;
    const int e = (int)(idx >> 5);
    const int j = (int)(idx & 31);
    if (e >= n_edges) return;
    const float m = vals[e] * x[(size_t)ecol[e] * OUT_FEAT + j];
    atomicAdd(&out[(size_t)erow[e] * OUT_FEAT + j], m);
}

// ---------------------------------------------------------------------------
extern "C" void kernel_launch(void* const* d_in, const int* in_sizes, int n_in,
                              void* d_out, int out_size, void* d_ws, size_t ws_size,
                              hipStream_t stream)
{
    const float* feat = (const float*)d_in[0];
    const float* W    = (const float*)d_in[1];
    const float* vals = (const float*)d_in[2];
    const int*   erow = (const int*)d_in[3];
    const int*   ecol = (const int*)d_in[4];
    float* out = (float*)d_out;

    const int n_nodes = in_sizes[0] / IN_FEAT;
    const int n_edges = in_sizes[2];
    const int nc = (n_nodes + RBC - 1) / RBC;     // 782 buckets

    // workspace: x 12.8 MB + buf1 16.0 MB + counters + obuf ~= 29.87 MB
    char* ws = (char*)d_ws;
    size_t off = 0;
    auto alloc = [&](size_t bytes) { size_t o = off; off = (off + bytes + 15) & ~(size_t)15; return o; };
    float*    x    = (float*)(ws + alloc((size_t)n_nodes * OUT_FEAT * sizeof(float)));
    uint2*    buf1 = (uint2*)(ws + alloc((size_t)nc * CAPC * sizeof(uint2)));
    size_t cnt_off = off;
    unsigned* cnt1 = (unsigned*)(ws + alloc((size_t)nc * CNT_STRIDE * sizeof(unsigned)));
    unsigned* ocnt = (unsigned*)(ws + alloc(sizeof(unsigned)));
    size_t cnt_end = (size_t)((char*)ocnt - ws) + 16;
    uint4*    obuf = (uint4*)(ws + alloc((size_t)OCAP * sizeof(uint4)));

    const double lam = (nc > 0) ? (double)n_edges / nc : 0.0;
    const bool sorted_path = (ws_size >= off) && (nc <= NC_MAX) &&
                             (lam + 8.0 * sqrt(lam + 1.0) <= (double)CAPC);

    // 1) x = feat @ W  (bf16 MFMA)
    {
        const int tiles = (n_nodes + 15) / 16;
        dim3 grid((tiles + 3) / 4);
        gemm_mfma_kernel<<<grid, 256, 0, stream>>>(feat, W, x, n_nodes);
    }

    if (sorted_path) {
        hipMemsetAsync(d_out, 0, (size_t)out_size * sizeof(float), stream);
        hipMemsetAsync(ws + cnt_off, 0, cnt_end - cnt_off, stream);

        const int nblk = (n_edges + L1_CHUNK - 1) / L1_CHUNK;
        part1_kernel<<<nblk, 512, 0, stream>>>(vals, erow, ecol, buf1, cnt1,
                                               ocnt, obuf, n_edges, nc);
        sort_kernel<<<nc, 512, 0, stream>>>(buf1, cnt1);
        scatter_seg_kernel<<<nc * (CAPC / SLOTS), 512, 0, stream>>>(buf1, cnt1, x, out);
        oflow_kernel<<<64, 256, 0, stream>>>(obuf, ocnt, x, out);
    } else {
        hipMemsetAsync(d_out, 0, (size_t)out_size * sizeof(float), stream);
        long long total = (long long)n_edges * OUT_FEAT;
        spmm_scatter_kernel<<<(unsigned)((total + 255) / 256), 256, 0, stream>>>(
            vals, erow, ecol, x, out, n_edges);
    }
}

// Round 11
// 128.728 us; speedup vs baseline: 3.2159x; 2.2902x over previous
//
#include <hip/hip_runtime.h>
#include <hip/hip_bf16.h>

#define IN_FEAT 256
#define OUT_FEAT 32

#define RBC 128          // rows per bucket
#define NC_MAX 1024      // max buckets (n_nodes <= 131072)
#define CAPC 2560        // capacity per bucket: lambda=2046 (+11 sigma)
#define L1_CHUNK 4096    // edges per part1 block
#define OCAP 16384       // overflow list capacity (shrunk to fit proven ws)
#define CNT_STRIDE 16    // u32 stride between counters (64B apart)

typedef __attribute__((ext_vector_type(8))) short short8;
typedef __attribute__((ext_vector_type(4))) float f32x4;

__device__ __forceinline__ unsigned cvt_pk_bf16(float lo, float hi) {
    unsigned r;
    asm volatile("v_cvt_pk_bf16_f32 %0, %1, %2" : "=v"(r) : "v"(lo), "v"(hi));
    return r;
}

// ---------------------------------------------------------------------------
// Kernel 1: x = feat @ W via bf16 MFMA (measured 27 us, unchanged).
// ---------------------------------------------------------------------------
__global__ __launch_bounds__(256) void gemm_mfma_kernel(
    const float* __restrict__ feat,
    const float* __restrict__ W,
    float* __restrict__ x,
    int n)
{
    __shared__ short sWT[OUT_FEAT][IN_FEAT + 8];

    const int tid = threadIdx.x;
    for (int i = tid; i < IN_FEAT * OUT_FEAT; i += 256) {
        const int k = i >> 5, c = i & 31;
        __hip_bfloat16 h = __float2bfloat16(W[i]);
        sWT[c][k] = *reinterpret_cast<short*>(&h);
    }
    __syncthreads();

    const int wid  = tid >> 6;
    const int lane = tid & 63;
    const int tile = blockIdx.x * 4 + wid;
    const int row0 = tile * 16;
    if (row0 >= n) return;

    const int l16 = lane & 15;
    const int lh  = lane >> 4;

    if (row0 + 16 <= n) {
        const int row = row0 + l16;
        const float4* fr = reinterpret_cast<const float4*>(feat) + (size_t)row * (IN_FEAT / 4);

        float4 ra[8][2];
        #pragma unroll
        for (int ks = 0; ks < 8; ++ks) {
            ra[ks][0] = fr[ks * 8 + lh * 2];
            ra[ks][1] = fr[ks * 8 + lh * 2 + 1];
        }

        f32x4 acc0 = {0.f, 0.f, 0.f, 0.f};
        f32x4 acc1 = {0.f, 0.f, 0.f, 0.f};

        #pragma unroll
        for (int ks = 0; ks < 8; ++ks) {
            union { short8 s; unsigned u[4]; } af;
            af.u[0] = cvt_pk_bf16(ra[ks][0].x, ra[ks][0].y);
            af.u[1] = cvt_pk_bf16(ra[ks][0].z, ra[ks][0].w);
            af.u[2] = cvt_pk_bf16(ra[ks][1].x, ra[ks][1].y);
            af.u[3] = cvt_pk_bf16(ra[ks][1].z, ra[ks][1].w);

            const int k0 = ks * 32 + lh * 8;
            short8 b0 = *reinterpret_cast<const short8*>(&sWT[l16][k0]);
            short8 b1 = *reinterpret_cast<const short8*>(&sWT[16 + l16][k0]);

            acc0 = __builtin_amdgcn_mfma_f32_16x16x32_bf16(af.s, b0, acc0, 0, 0, 0);
            acc1 = __builtin_amdgcn_mfma_f32_16x16x32_bf16(af.s, b1, acc1, 0, 0, 0);
        }

        #pragma unroll
        for (int r = 0; r < 4; ++r) {
            const size_t orow = (size_t)(row0 + lh * 4 + r) * OUT_FEAT;
            x[orow + l16]      = acc0[r];
            x[orow + 16 + l16] = acc1[r];
        }
    } else {
        const int rows = n - row0;
        for (int idx = lane; idx < rows * OUT_FEAT; idx += 64) {
            const int r = idx >> 5, j = idx & 31;
            float a = 0.f;
            for (int k = 0; k < IN_FEAT; ++k) {
                unsigned wb = ((unsigned)(unsigned short)sWT[j][k]) << 16;
                a += feat[(size_t)(row0 + r) * IN_FEAT + k] * __uint_as_float(wb);
            }
            x[(size_t)(row0 + r) * OUT_FEAT + j] = a;
        }
    }
}

// ---------------------------------------------------------------------------
// Kernel 2: partition edges into 128-row buckets (row>>7). Proven ~20us.
//   Entry {meta=(row&127)<<17|col, valbits}.
// ---------------------------------------------------------------------------
__global__ __launch_bounds__(512) void part1_kernel(
    const float* __restrict__ vals,
    const int* __restrict__ erow,
    const int* __restrict__ ecol,
    uint2* __restrict__ buf1,
    unsigned* __restrict__ cnt1,
    unsigned* __restrict__ ocnt,
    uint4* __restrict__ obuf,
    int n_edges, int nc)
{
    __shared__ uint2 sE[L1_CHUNK];                 // 32 KB
    __shared__ unsigned short sBkt[L1_CHUNK];      // 8 KB
    __shared__ unsigned sHist[NC_MAX], sBase[NC_MAX], sCur[NC_MAX], sGBase[NC_MAX];

    const int tid = threadIdx.x;
    const int chunk0 = blockIdx.x * L1_CHUNK;
    const int nq = n_edges >> 2;

    for (int b = tid; b < nc; b += 512) { sHist[b] = 0; sCur[b] = 0; }
    __syncthreads();

    int4 r4[2]; int4 c4[2]; float4 v4[2];
    #pragma unroll
    for (int i = 0; i < 2; ++i) {
        const int qi = (chunk0 >> 2) + tid + i * 512;
        if (qi < nq) {
            r4[i] = reinterpret_cast<const int4*>(erow)[qi];
            c4[i] = reinterpret_cast<const int4*>(ecol)[qi];
            v4[i] = reinterpret_cast<const float4*>(vals)[qi];
        } else {
            r4[i] = make_int4(-1, -1, -1, -1);
            c4[i] = make_int4(0, 0, 0, 0);
            v4[i] = make_float4(0.f, 0.f, 0.f, 0.f);
        }
    }

    #pragma unroll
    for (int i = 0; i < 2; ++i) {
        const int* rr = &r4[i].x;
        #pragma unroll
        for (int t = 0; t < 4; ++t)
            if (rr[t] >= 0) atomicAdd(&sHist[rr[t] >> 7], 1u);
    }
    __syncthreads();

    if (tid == 0) {
        unsigned s = 0;
        for (int b = 0; b < nc; ++b) { sBase[b] = s; s += sHist[b]; }
    }
    __syncthreads();

    for (int b = tid; b < nc; b += 512)
        sGBase[b] = sHist[b] ? atomicAdd(&cnt1[(size_t)b * CNT_STRIDE], sHist[b]) : 0u;
    __syncthreads();

    #pragma unroll
    for (int i = 0; i < 2; ++i) {
        const int*   rr = &r4[i].x;
        const int*   cc = &c4[i].x;
        const float* vv = &v4[i].x;
        #pragma unroll
        for (int t = 0; t < 4; ++t) {
            const int r = rr[t];
            if (r >= 0) {
                const int cb = r >> 7;
                unsigned p = sBase[cb] + atomicAdd(&sCur[cb], 1u);
                sE[p] = make_uint2(((unsigned)(r & 127) << 17) | (unsigned)cc[t],
                                   __float_as_uint(vv[t]));
                sBkt[p] = (unsigned short)cb;
            }
        }
    }
    __syncthreads();

    int total = n_edges - chunk0;
    if (total > L1_CHUNK) total = L1_CHUNK;
    for (int p = tid; p < total; p += 512) {
        const int cb = sBkt[p];
        const unsigned g = sGBase[cb] + (p - sBase[cb]);
        const uint2 e = sE[p];
        if (g < CAPC) {
            buf1[(size_t)cb * CAPC + g] = e;
        } else {
            unsigned o = atomicAdd(ocnt, 1u);
            if (o < OCAP)
                obuf[o] = make_uint4(((unsigned)cb << 7) | (e.x >> 17),
                                     e.x & 0x1FFFFu, e.y, 0u);
        }
    }

    if (blockIdx.x == 0 && tid < (n_edges & 3)) {
        const int e = (nq << 2) + tid;
        unsigned o = atomicAdd(ocnt, 1u);
        if (o < OCAP)
            obuf[o] = make_uint4((unsigned)erow[e], (unsigned)ecol[e],
                                 __float_as_uint(vals[e]), 0u);
    }
}

// ---------------------------------------------------------------------------
// Kernel 3: in-place counting sort of each bucket by local row (proven ~15us)
//   + NEW: emit per-row CSR pointers (rstart = abs index into buf1, rcnt).
// ---------------------------------------------------------------------------
__global__ __launch_bounds__(512) void sort_kernel(
    uint2* __restrict__ buf1,
    const unsigned* __restrict__ cnt1,
    unsigned* __restrict__ rstart,
    unsigned* __restrict__ rcnt)
{
    __shared__ uint2 sorted[CAPC];                       // 20 KB
    __shared__ unsigned h[RBC], base[RBC], cur[RBC];

    const int tid = threadIdx.x;
    const int b = blockIdx.x;
    unsigned n = cnt1[(size_t)b * CNT_STRIDE];
    if (n > CAPC) n = CAPC;
    uint2* eb = buf1 + (size_t)b * CAPC;

    if (tid < RBC) { h[tid] = 0; cur[tid] = 0; }
    __syncthreads();

    uint2 e[5];   // 5*512 = 2560 = CAPC
    #pragma unroll
    for (int i = 0; i < 5; ++i) {
        const int p = tid + i * 512;
        e[i] = (p < (int)n) ? eb[p] : make_uint2(0xFFFFFFFFu, 0u);  // valid meta < 2^24
    }
    #pragma unroll
    for (int i = 0; i < 5; ++i)
        if (e[i].x != 0xFFFFFFFFu) atomicAdd(&h[(e[i].x >> 17) & 127u], 1u);
    __syncthreads();

    if (tid == 0) {
        unsigned s = 0;
        for (int r = 0; r < RBC; ++r) { base[r] = s; s += h[r]; }
    }
    __syncthreads();

    #pragma unroll
    for (int i = 0; i < 5; ++i) {
        if (e[i].x != 0xFFFFFFFFu) {
            const unsigned r = (e[i].x >> 17) & 127u;
            const unsigned p = base[r] + atomicAdd(&cur[r], 1u);
            sorted[p] = e[i];
        }
    }
    __syncthreads();

    for (int i = tid; i < (int)n; i += 512) eb[i] = sorted[i];

    // CSR row pointers: global row = b*RBC + tid
    if (tid < RBC) {
        rstart[b * RBC + tid] = (unsigned)(b * CAPC) + base[tid];
        rcnt[b * RBC + tid]   = h[tid];
    }
}

// ---------------------------------------------------------------------------
// Kernel 4: CSR row-gather SpMM — ZERO atomics, ZERO LDS.
//   One wave per output row. Lanes = 2 edge-slots x 32 features.
//   Register accumulation over the row's sorted run; 2-deep unrolled
//   independent gathers (round-4-GEMM pattern, proven to pipeline);
//   one shfl merge; plain coalesced 128B row store (full coverage ->
//   no out memset). Aux cost per edge-feature: 1 L1-resident entry read.
// ---------------------------------------------------------------------------
__global__ __launch_bounds__(256) void row_spmm_kernel(
    const uint2* __restrict__ buf1,
    const unsigned* __restrict__ rstart,
    const unsigned* __restrict__ rcnt,
    const float* __restrict__ x,
    float* __restrict__ out,
    int n_nodes)
{
    const int wid  = threadIdx.x >> 6;
    const int lane = threadIdx.x & 63;
    const int row  = blockIdx.x * 4 + wid;
    if (row >= n_nodes) return;

    const unsigned s  = rstart[row];
    const unsigned cn = rcnt[row];
    const unsigned e2 = lane >> 5;   // edge slot 0/1
    const int j = lane & 31;         // feature

    float acc = 0.f;
    unsigned e = e2;
    for (; e + 2 < cn; e += 4) {
        const uint2 pa = buf1[s + e];
        const uint2 pb = buf1[s + e + 2];
        const float xa = x[(size_t)(pa.x & 0x1FFFFu) * OUT_FEAT + j];
        const float xb = x[(size_t)(pb.x & 0x1FFFFu) * OUT_FEAT + j];
        acc += __uint_as_float(pa.y) * xa + __uint_as_float(pb.y) * xb;
    }
    if (e < cn) {
        const uint2 p = buf1[s + e];
        acc += __uint_as_float(p.y) * x[(size_t)(p.x & 0x1FFFFu) * OUT_FEAT + j];
    }

    // merge the two edge slots: lane j += lane j+32
    acc += __shfl_down(acc, 32, 64);
    if (e2 == 0)
        out[(size_t)row * OUT_FEAT + j] = acc;
}

// ---------------------------------------------------------------------------
// Kernel 5: overflow cleanup (expected zero work). Runs AFTER row_spmm
//   (atomically adds on top of the plain-stored rows).
// ---------------------------------------------------------------------------
__global__ __launch_bounds__(256) void oflow_kernel(
    const uint4* __restrict__ obuf,
    const unsigned* __restrict__ ocnt,
    const float* __restrict__ x,
    float* __restrict__ out)
{
    unsigned n = *ocnt;
    if (n > OCAP) n = OCAP;
    const long long total = (long long)n * OUT_FEAT;
    const long long stride = (long long)gridDim.x * blockDim.x;
    for (long long idx = blockIdx.x * (long long)blockDim.x + threadIdx.x;
         idx < total; idx += stride) {
        const int e = (int)(idx >> 5), j = (int)(idx & 31);
        uint4 p = obuf[e];
        atomicAdd(&out[(size_t)p.x * OUT_FEAT + j],
                  __uint_as_float(p.z) * x[(size_t)p.y * OUT_FEAT + j]);
    }
}

// ---------------------------------------------------------------------------
// Fallback: flat atomic scatter (measured 171 us) if ws/shape gate fails.
// ---------------------------------------------------------------------------
__global__ __launch_bounds__(256) void spmm_scatter_kernel(
    const float* __restrict__ vals,
    const int* __restrict__ erow,
    const int* __restrict__ ecol,
    const float* __restrict__ x,
    float* __restrict__ out,
    int n_edges)
{
    const long long idx = (long long)blockIdx.x * blockDim.x + threadIdx.x;
    const int e = (int)(idx >> 5);
    const int j = (int)(idx & 31);
    if (e >= n_edges) return;
    const float m = vals[e] * x[(size_t)ecol[e] * OUT_FEAT + j];
    atomicAdd(&out[(size_t)erow[e] * OUT_FEAT + j], m);
}

// ---------------------------------------------------------------------------
extern "C" void kernel_launch(void* const* d_in, const int* in_sizes, int n_in,
                              void* d_out, int out_size, void* d_ws, size_t ws_size,
                              hipStream_t stream)
{
    const float* feat = (const float*)d_in[0];
    const float* W    = (const float*)d_in[1];
    const float* vals = (const float*)d_in[2];
    const int*   erow = (const int*)d_in[3];
    const int*   ecol = (const int*)d_in[4];
    float* out = (float*)d_out;

    const int n_nodes = in_sizes[0] / IN_FEAT;
    const int n_edges = in_sizes[2];
    const int nc = (n_nodes + RBC - 1) / RBC;     // 782 buckets

    // workspace: x 12.21 + buf1 15.27 + cnt 0.05 + rptr 0.76 + obuf 0.25 MB
    //          = 29.93 MB <= proven 29.95 MB
    char* ws = (char*)d_ws;
    size_t off = 0;
    auto alloc = [&](size_t bytes) { size_t o = off; off = (off + bytes + 15) & ~(size_t)15; return o; };
    float*    x      = (float*)(ws + alloc((size_t)n_nodes * OUT_FEAT * sizeof(float)));
    uint2*    buf1   = (uint2*)(ws + alloc((size_t)nc * CAPC * sizeof(uint2)));
    size_t cnt_off = off;
    unsigned* cnt1   = (unsigned*)(ws + alloc((size_t)nc * CNT_STRIDE * sizeof(unsigned)));
    unsigned* ocnt   = (unsigned*)(ws + alloc(sizeof(unsigned)));
    size_t cnt_end = (size_t)((char*)ocnt - ws) + 16;
    unsigned* rstart = (unsigned*)(ws + alloc((size_t)nc * RBC * sizeof(unsigned)));
    unsigned* rcnt   = (unsigned*)(ws + alloc((size_t)nc * RBC * sizeof(unsigned)));
    uint4*    obuf   = (uint4*)(ws + alloc((size_t)OCAP * sizeof(uint4)));

    const double lam = (nc > 0) ? (double)n_edges / nc : 0.0;
    const bool sorted_path = (ws_size >= off) && (nc <= NC_MAX) &&
                             (lam + 8.0 * sqrt(lam + 1.0) <= (double)CAPC);

    // 1) x = feat @ W  (bf16 MFMA)
    {
        const int tiles = (n_nodes + 15) / 16;
        dim3 grid((tiles + 3) / 4);
        gemm_mfma_kernel<<<grid, 256, 0, stream>>>(feat, W, x, n_nodes);
    }

    if (sorted_path) {
        hipMemsetAsync(ws + cnt_off, 0, cnt_end - cnt_off, stream);

        const int nblk = (n_edges + L1_CHUNK - 1) / L1_CHUNK;
        part1_kernel<<<nblk, 512, 0, stream>>>(vals, erow, ecol, buf1, cnt1,
                                               ocnt, obuf, n_edges, nc);
        sort_kernel<<<nc, 512, 0, stream>>>(buf1, cnt1, rstart, rcnt);
        row_spmm_kernel<<<(n_nodes + 3) / 4, 256, 0, stream>>>(buf1, rstart, rcnt,
                                                               x, out, n_nodes);
        oflow_kernel<<<64, 256, 0, stream>>>(obuf, ocnt, x, out);
    } else {
        hipMemsetAsync(d_out, 0, (size_t)out_size * sizeof(float), stream);
        long long total = (long long)n_edges * OUT_FEAT;
        spmm_scatter_kernel<<<(unsigned)((total + 255) / 256), 256, 0, stream>>>(
            vals, erow, ecol, x, out, n_edges);
    }
}

// Round 12
// 109.557 us; speedup vs baseline: 3.7786x; 1.1750x over previous
//
#include <hip/hip_runtime.h>
#include <hip/hip_bf16.h>

#define IN_FEAT 256
#define OUT_FEAT 32

#define RBC 128          // rows per bucket
#define NC_MAX 1024      // max buckets (n_nodes <= 131072)
#define CAPC 2560        // capacity per bucket: lambda=2046 (+11 sigma)
#define L1_CHUNK 4096    // edges per part1 block
#define OCAP 16384       // overflow list capacity
#define CNT_STRIDE 16    // u32 stride between counters (64B apart)

typedef __attribute__((ext_vector_type(8))) short short8;
typedef __attribute__((ext_vector_type(4))) float f32x4;

__device__ __forceinline__ unsigned cvt_pk_bf16(float lo, float hi) {
    unsigned r;
    asm volatile("v_cvt_pk_bf16_f32 %0, %1, %2" : "=v"(r) : "v"(lo), "v"(hi));
    return r;
}
__device__ __forceinline__ float bf16lo(unsigned w) { return __uint_as_float(w << 16); }
__device__ __forceinline__ float bf16hi(unsigned w) { return __uint_as_float(w & 0xFFFF0000u); }
__device__ __forceinline__ float bf16s(unsigned short u) { return __uint_as_float(((unsigned)u) << 16); }

// ---------------------------------------------------------------------------
// Kernel 1: x = feat @ W via bf16 MFMA; x stored as BF16 (halves the
//   consumer's gather bytes: 12.8 -> 6.4 MB, row read 128 -> 64 B).
// ---------------------------------------------------------------------------
__global__ __launch_bounds__(256) void gemm_mfma_kernel(
    const float* __restrict__ feat,
    const float* __restrict__ W,
    unsigned short* __restrict__ x16,
    int n)
{
    __shared__ short sWT[OUT_FEAT][IN_FEAT + 8];

    const int tid = threadIdx.x;
    for (int i = tid; i < IN_FEAT * OUT_FEAT; i += 256) {
        const int k = i >> 5, c = i & 31;
        __hip_bfloat16 h = __float2bfloat16(W[i]);
        sWT[c][k] = *reinterpret_cast<short*>(&h);
    }
    __syncthreads();

    const int wid  = tid >> 6;
    const int lane = tid & 63;
    const int tile = blockIdx.x * 4 + wid;
    const int row0 = tile * 16;
    if (row0 >= n) return;

    const int l16 = lane & 15;
    const int lh  = lane >> 4;

    if (row0 + 16 <= n) {
        const int row = row0 + l16;
        const float4* fr = reinterpret_cast<const float4*>(feat) + (size_t)row * (IN_FEAT / 4);

        float4 ra[8][2];
        #pragma unroll
        for (int ks = 0; ks < 8; ++ks) {
            ra[ks][0] = fr[ks * 8 + lh * 2];
            ra[ks][1] = fr[ks * 8 + lh * 2 + 1];
        }

        f32x4 acc0 = {0.f, 0.f, 0.f, 0.f};
        f32x4 acc1 = {0.f, 0.f, 0.f, 0.f};

        #pragma unroll
        for (int ks = 0; ks < 8; ++ks) {
            union { short8 s; unsigned u[4]; } af;
            af.u[0] = cvt_pk_bf16(ra[ks][0].x, ra[ks][0].y);
            af.u[1] = cvt_pk_bf16(ra[ks][0].z, ra[ks][0].w);
            af.u[2] = cvt_pk_bf16(ra[ks][1].x, ra[ks][1].y);
            af.u[3] = cvt_pk_bf16(ra[ks][1].z, ra[ks][1].w);

            const int k0 = ks * 32 + lh * 8;
            short8 b0 = *reinterpret_cast<const short8*>(&sWT[l16][k0]);
            short8 b1 = *reinterpret_cast<const short8*>(&sWT[16 + l16][k0]);

            acc0 = __builtin_amdgcn_mfma_f32_16x16x32_bf16(af.s, b0, acc0, 0, 0, 0);
            acc1 = __builtin_amdgcn_mfma_f32_16x16x32_bf16(af.s, b1, acc1, 0, 0, 0);
        }

        // D: col = lane&15 (acc0) / +16 (acc1), row = (lane>>4)*4 + r
        #pragma unroll
        for (int r = 0; r < 4; ++r) {
            const size_t orow = (size_t)(row0 + lh * 4 + r) * OUT_FEAT;
            const unsigned pk = cvt_pk_bf16(acc0[r], acc1[r]);
            x16[orow + l16]      = (unsigned short)(pk & 0xFFFFu);
            x16[orow + 16 + l16] = (unsigned short)(pk >> 16);
        }
    } else {
        const int rows = n - row0;
        for (int idx = lane; idx < rows * OUT_FEAT; idx += 64) {
            const int r = idx >> 5, j = idx & 31;
            float a = 0.f;
            for (int k = 0; k < IN_FEAT; ++k) {
                unsigned wb = ((unsigned)(unsigned short)sWT[j][k]) << 16;
                a += feat[(size_t)(row0 + r) * IN_FEAT + k] * __uint_as_float(wb);
            }
            x16[(size_t)(row0 + r) * OUT_FEAT + j] =
                (unsigned short)(cvt_pk_bf16(a, 0.f) & 0xFFFFu);
        }
    }
}

// ---------------------------------------------------------------------------
// Kernel 1b: zero the bucket counters + overflow counter (replaces the
//   rocclr fillBuffer; tiny, deterministic).
// ---------------------------------------------------------------------------
__global__ __launch_bounds__(256) void zero_cnt_kernel(
    unsigned* __restrict__ p, int n_u32)
{
    const int i = blockIdx.x * 256 + threadIdx.x;
    if (i < n_u32) p[i] = 0u;
}

// ---------------------------------------------------------------------------
// Kernel 2: partition edges into 128-row buckets (row>>7). Proven.
//   Entry {meta=(row&127)<<17|col, valbits}.
// ---------------------------------------------------------------------------
__global__ __launch_bounds__(512) void part1_kernel(
    const float* __restrict__ vals,
    const int* __restrict__ erow,
    const int* __restrict__ ecol,
    uint2* __restrict__ buf1,
    unsigned* __restrict__ cnt1,
    unsigned* __restrict__ ocnt,
    uint4* __restrict__ obuf,
    int n_edges, int nc)
{
    __shared__ uint2 sE[L1_CHUNK];                 // 32 KB
    __shared__ unsigned short sBkt[L1_CHUNK];      // 8 KB
    __shared__ unsigned sHist[NC_MAX], sBase[NC_MAX], sCur[NC_MAX], sGBase[NC_MAX];

    const int tid = threadIdx.x;
    const int chunk0 = blockIdx.x * L1_CHUNK;
    const int nq = n_edges >> 2;

    for (int b = tid; b < nc; b += 512) { sHist[b] = 0; sCur[b] = 0; }
    __syncthreads();

    int4 r4[2]; int4 c4[2]; float4 v4[2];
    #pragma unroll
    for (int i = 0; i < 2; ++i) {
        const int qi = (chunk0 >> 2) + tid + i * 512;
        if (qi < nq) {
            r4[i] = reinterpret_cast<const int4*>(erow)[qi];
            c4[i] = reinterpret_cast<const int4*>(ecol)[qi];
            v4[i] = reinterpret_cast<const float4*>(vals)[qi];
        } else {
            r4[i] = make_int4(-1, -1, -1, -1);
            c4[i] = make_int4(0, 0, 0, 0);
            v4[i] = make_float4(0.f, 0.f, 0.f, 0.f);
        }
    }

    #pragma unroll
    for (int i = 0; i < 2; ++i) {
        const int* rr = &r4[i].x;
        #pragma unroll
        for (int t = 0; t < 4; ++t)
            if (rr[t] >= 0) atomicAdd(&sHist[rr[t] >> 7], 1u);
    }
    __syncthreads();

    if (tid == 0) {
        unsigned s = 0;
        for (int b = 0; b < nc; ++b) { sBase[b] = s; s += sHist[b]; }
    }
    __syncthreads();

    for (int b = tid; b < nc; b += 512)
        sGBase[b] = sHist[b] ? atomicAdd(&cnt1[(size_t)b * CNT_STRIDE], sHist[b]) : 0u;
    __syncthreads();

    #pragma unroll
    for (int i = 0; i < 2; ++i) {
        const int*   rr = &r4[i].x;
        const int*   cc = &c4[i].x;
        const float* vv = &v4[i].x;
        #pragma unroll
        for (int t = 0; t < 4; ++t) {
            const int r = rr[t];
            if (r >= 0) {
                const int cb = r >> 7;
                unsigned p = sBase[cb] + atomicAdd(&sCur[cb], 1u);
                sE[p] = make_uint2(((unsigned)(r & 127) << 17) | (unsigned)cc[t],
                                   __float_as_uint(vv[t]));
                sBkt[p] = (unsigned short)cb;
            }
        }
    }
    __syncthreads();

    int total = n_edges - chunk0;
    if (total > L1_CHUNK) total = L1_CHUNK;
    for (int p = tid; p < total; p += 512) {
        const int cb = sBkt[p];
        const unsigned g = sGBase[cb] + (p - sBase[cb]);
        const uint2 e = sE[p];
        if (g < CAPC) {
            buf1[(size_t)cb * CAPC + g] = e;
        } else {
            unsigned o = atomicAdd(ocnt, 1u);
            if (o < OCAP)
                obuf[o] = make_uint4(((unsigned)cb << 7) | (e.x >> 17),
                                     e.x & 0x1FFFFu, e.y, 0u);
        }
    }

    if (blockIdx.x == 0 && tid < (n_edges & 3)) {
        const int e = (nq << 2) + tid;
        unsigned o = atomicAdd(ocnt, 1u);
        if (o < OCAP)
            obuf[o] = make_uint4((unsigned)erow[e], (unsigned)ecol[e],
                                 __float_as_uint(vals[e]), 0u);
    }
}

// ---------------------------------------------------------------------------
// Kernel 3: in-place counting sort of each bucket by local row + CSR emit.
// ---------------------------------------------------------------------------
__global__ __launch_bounds__(512) void sort_kernel(
    uint2* __restrict__ buf1,
    const unsigned* __restrict__ cnt1,
    unsigned* __restrict__ rstart,
    unsigned* __restrict__ rcnt)
{
    __shared__ uint2 sorted[CAPC];                       // 20 KB
    __shared__ unsigned h[RBC], base[RBC], cur[RBC];

    const int tid = threadIdx.x;
    const int b = blockIdx.x;
    unsigned n = cnt1[(size_t)b * CNT_STRIDE];
    if (n > CAPC) n = CAPC;
    uint2* eb = buf1 + (size_t)b * CAPC;

    if (tid < RBC) { h[tid] = 0; cur[tid] = 0; }
    __syncthreads();

    uint2 e[5];   // 5*512 = 2560 = CAPC
    #pragma unroll
    for (int i = 0; i < 5; ++i) {
        const int p = tid + i * 512;
        e[i] = (p < (int)n) ? eb[p] : make_uint2(0xFFFFFFFFu, 0u);
    }
    #pragma unroll
    for (int i = 0; i < 5; ++i)
        if (e[i].x != 0xFFFFFFFFu) atomicAdd(&h[(e[i].x >> 17) & 127u], 1u);
    __syncthreads();

    if (tid == 0) {
        unsigned s = 0;
        for (int r = 0; r < RBC; ++r) { base[r] = s; s += h[r]; }
    }
    __syncthreads();

    #pragma unroll
    for (int i = 0; i < 5; ++i) {
        if (e[i].x != 0xFFFFFFFFu) {
            const unsigned r = (e[i].x >> 17) & 127u;
            const unsigned p = base[r] + atomicAdd(&cur[r], 1u);
            sorted[p] = e[i];
        }
    }
    __syncthreads();

    for (int i = tid; i < (int)n; i += 512) eb[i] = sorted[i];

    if (tid < RBC) {
        rstart[b * RBC + tid] = (unsigned)(b * CAPC) + base[tid];
        rcnt[b * RBC + tid]   = h[tid];
    }
}

// ---------------------------------------------------------------------------
// Kernel 4: CSR row-gather SpMM, bf16 x — zero atomics, zero LDS.
//   Wave = 4 edge-slots x 16 lanes (lane reads 1 uint = 2 packed bf16
//   feats): 4 independent gathers/iter, 2-deep unroll -> 8 in flight.
//   Merge via 2 shfl_downs; float2 row store (full coverage, no memset).
// ---------------------------------------------------------------------------
__global__ __launch_bounds__(256) void row_spmm_kernel(
    const uint2* __restrict__ buf1,
    const unsigned* __restrict__ rstart,
    const unsigned* __restrict__ rcnt,
    const unsigned* __restrict__ xw,   // x as bf16, read as uints (16/row)
    float* __restrict__ out,
    int n_nodes)
{
    const int wid  = threadIdx.x >> 6;
    const int lane = threadIdx.x & 63;
    const int row  = blockIdx.x * 4 + wid;
    if (row >= n_nodes) return;

    const unsigned s  = rstart[row];
    const unsigned cn = rcnt[row];
    const int slot = lane >> 4;      // 0..3
    const int jp   = lane & 15;      // feature pair (feats 2jp, 2jp+1)

    float aLo = 0.f, aHi = 0.f;
    unsigned e = (unsigned)slot;
    for (; e + 4 < cn; e += 8) {
        const uint2 pa = buf1[s + e];
        const uint2 pb = buf1[s + e + 4];
        const unsigned wa = xw[(size_t)(pa.x & 0x1FFFFu) * 16 + jp];
        const unsigned wb = xw[(size_t)(pb.x & 0x1FFFFu) * 16 + jp];
        const float va = __uint_as_float(pa.y);
        const float vb = __uint_as_float(pb.y);
        aLo += va * bf16lo(wa) + vb * bf16lo(wb);
        aHi += va * bf16hi(wa) + vb * bf16hi(wb);
    }
    for (; e < cn; e += 4) {
        const uint2 p = buf1[s + e];
        const unsigned w = xw[(size_t)(p.x & 0x1FFFFu) * 16 + jp];
        const float v = __uint_as_float(p.y);
        aLo += v * bf16lo(w);
        aHi += v * bf16hi(w);
    }

    // reduce 4 slots -> slot 0
    aLo += __shfl_down(aLo, 32, 64);
    aHi += __shfl_down(aHi, 32, 64);
    aLo += __shfl_down(aLo, 16, 64);
    aHi += __shfl_down(aHi, 16, 64);

    if (slot == 0) {
        float2 v = make_float2(aLo, aHi);
        *reinterpret_cast<float2*>(&out[(size_t)row * OUT_FEAT + 2 * jp]) = v;
    }
}

// ---------------------------------------------------------------------------
// Kernel 5: overflow cleanup (expected zero work). Atomic add on top of
//   the plain-stored rows; runs after row_spmm.
// ---------------------------------------------------------------------------
__global__ __launch_bounds__(256) void oflow_kernel(
    const uint4* __restrict__ obuf,
    const unsigned* __restrict__ ocnt,
    const unsigned short* __restrict__ x16,
    float* __restrict__ out)
{
    unsigned n = *ocnt;
    if (n > OCAP) n = OCAP;
    const long long total = (long long)n * OUT_FEAT;
    const long long stride = (long long)gridDim.x * blockDim.x;
    for (long long idx = blockIdx.x * (long long)blockDim.x + threadIdx.x;
         idx < total; idx += stride) {
        const int e = (int)(idx >> 5), j = (int)(idx & 31);
        uint4 p = obuf[e];
        atomicAdd(&out[(size_t)p.x * OUT_FEAT + j],
                  __uint_as_float(p.z) * bf16s(x16[(size_t)p.y * OUT_FEAT + j]));
    }
}

// ---------------------------------------------------------------------------
// Fallback: flat atomic scatter (bf16 x) if ws/shape gate fails.
// ---------------------------------------------------------------------------
__global__ __launch_bounds__(256) void spmm_scatter_kernel(
    const float* __restrict__ vals,
    const int* __restrict__ erow,
    const int* __restrict__ ecol,
    const unsigned short* __restrict__ x16,
    float* __restrict__ out,
    int n_edges)
{
    const long long idx = (long long)blockIdx.x * blockDim.x + threadIdx.x;
    const int e = (int)(idx >> 5);
    const int j = (int)(idx & 31);
    if (e >= n_edges) return;
    const float m = vals[e] * bf16s(x16[(size_t)ecol[e] * OUT_FEAT + j]);
    atomicAdd(&out[(size_t)erow[e] * OUT_FEAT + j], m);
}

// ---------------------------------------------------------------------------
extern "C" void kernel_launch(void* const* d_in, const int* in_sizes, int n_in,
                              void* d_out, int out_size, void* d_ws, size_t ws_size,
                              hipStream_t stream)
{
    const float* feat = (const float*)d_in[0];
    const float* W    = (const float*)d_in[1];
    const float* vals = (const float*)d_in[2];
    const int*   erow = (const int*)d_in[3];
    const int*   ecol = (const int*)d_in[4];
    float* out = (float*)d_out;

    const int n_nodes = in_sizes[0] / IN_FEAT;
    const int n_edges = in_sizes[2];
    const int nc = (n_nodes + RBC - 1) / RBC;     // 782 buckets

    // workspace: x16 6.1 + buf1 15.3 + cnt 0.05 + rptr 0.76 + obuf 0.25 MB
    char* ws = (char*)d_ws;
    size_t off = 0;
    auto alloc = [&](size_t bytes) { size_t o = off; off = (off + bytes + 15) & ~(size_t)15; return o; };
    unsigned short* x16 = (unsigned short*)(ws + alloc((size_t)n_nodes * OUT_FEAT * sizeof(unsigned short)));
    uint2*    buf1   = (uint2*)(ws + alloc((size_t)nc * CAPC * sizeof(uint2)));
    size_t cnt_off = off;
    unsigned* cnt1   = (unsigned*)(ws + alloc((size_t)nc * CNT_STRIDE * sizeof(unsigned)));
    unsigned* ocnt   = (unsigned*)(ws + alloc(sizeof(unsigned)));
    unsigned* rstart = (unsigned*)(ws + alloc((size_t)nc * RBC * sizeof(unsigned)));
    unsigned* rcnt   = (unsigned*)(ws + alloc((size_t)nc * RBC * sizeof(unsigned)));
    uint4*    obuf   = (uint4*)(ws + alloc((size_t)OCAP * sizeof(uint4)));

    const double lam = (nc > 0) ? (double)n_edges / nc : 0.0;
    const bool sorted_path = (ws_size >= off) && (nc <= NC_MAX) &&
                             (lam + 8.0 * sqrt(lam + 1.0) <= (double)CAPC);

    // 1) x = feat @ W  (bf16 MFMA, bf16 x)
    {
        const int tiles = (n_nodes + 15) / 16;
        dim3 grid((tiles + 3) / 4);
        gemm_mfma_kernel<<<grid, 256, 0, stream>>>(feat, W, x16, n_nodes);
    }

    if (sorted_path) {
        // zero cnt1 + ocnt via kernel (covers the contiguous counter region)
        const int zn = (int)((cnt_off == 0 ? 0 : 0), (nc * CNT_STRIDE + 4));
        zero_cnt_kernel<<<(zn + 255) / 256, 256, 0, stream>>>(cnt1, zn);

        const int nblk = (n_edges + L1_CHUNK - 1) / L1_CHUNK;
        part1_kernel<<<nblk, 512, 0, stream>>>(vals, erow, ecol, buf1, cnt1,
                                               ocnt, obuf, n_edges, nc);
        sort_kernel<<<nc, 512, 0, stream>>>(buf1, cnt1, rstart, rcnt);
        row_spmm_kernel<<<(n_nodes + 3) / 4, 256, 0, stream>>>(
            buf1, rstart, rcnt, (const unsigned*)x16, out, n_nodes);
        oflow_kernel<<<64, 256, 0, stream>>>(obuf, ocnt, x16, out);
    } else {
        hipMemsetAsync(d_out, 0, (size_t)out_size * sizeof(float), stream);
        long long total = (long long)n_edges * OUT_FEAT;
        spmm_scatter_kernel<<<(unsigned)((total + 255) / 256), 256, 0, stream>>>(
            vals, erow, ecol, x16, out, n_edges);
    }
}